// Round 4
// baseline (247.564 us; speedup 1.0000x reference)
//
#include <hip/hip_runtime.h>

// NCC forces, 192^3 fp32. Round 4: LDS-pipe focus (model: R3 was LDS-bound,
// ~1320 DS-cycles per block-iter).
//  - x-sums computed IN REGISTERS by stager lanes from their own global loads
//    (float4 + 2x float2 = 8-wide window, sliding-window 5 fields), written as
//    one float4 per field -> zero x-phase LDS reads.
//  - y-sums: 320 chunk-of-4 sliding tasks (8 strided rd + sliding) -> box buf.
//  - z-grad centers in per-thread register ring (saves 6 rd/voxel).
//  - raw ring 4-deep (only x/y-grad slice + fresh slice live) -> 28.8 KB LDS,
//    2 barriers/iter, no trailing barrier (slot disjointness).
//  - NT stores reverted (R3: WRITE 83->103 MB, partial-line streamout).
//  - ZSEG 16 -> 1728 blocks; XCD swizzle kept (R3: FETCH 226->71 MB).

#define DD 192
#define HH 192
#define WW 192
#define NVOX (DD * HH * WW)
#define TS 16
#define RR 20            // staged rows (y halo)
#define RW 24            // raw row width (x0-4 .. x0+19)
#define ZSEG 16
#define NBX 12
#define NBY 12
#define NBZ 12           // 192/16
#define PER_XCD ((NBX * NBY * NBZ) / 8)   // 216

__global__ __launch_bounds__(256)
void ncc_forces_kernel(const float* __restrict__ mimg,
                       const float* __restrict__ fimg,
                       const int*   __restrict__ mmask,
                       const int*   __restrict__ fmask,
                       float* __restrict__ out)
{
    __shared__ float rawm[4][RR][RW];   // 7680 B
    __shared__ float rawf[4][RR][RW];   // 7680 B
    __shared__ float xs[5][RR][20];     // 8000 B  (x-sums, y-pitch-major rows, x pitch 20)
    __shared__ float box[5][TS][17];    // 5440 B  (2D sums, [f][x][y], pitch 17) => 28.8 KB

    // XCD swizzle: XCD k gets 216 consecutive logical blocks (z-slab locality)
    const int b  = blockIdx.x;
    const int L  = (b & 7) * PER_XCD + (b >> 3);
    const int bz = L / (NBX * NBY);
    const int r0_ = L - bz * (NBX * NBY);
    const int by = r0_ / NBX;
    const int bx = r0_ - by * NBX;

    const int tid = threadIdx.x;
    const int tx = tid & 15;
    const int ty = tid >> 4;
    const int x0 = bx * TS, y0 = by * TS, z0 = bz * ZSEG;

    // ---- roles ----
    // lanes 0..79  : xs-stagers  (20 rows x 4 output-quads)
    // lanes 80..199: raw-stagers (20 rows x 6 quads, both images)
    const bool is_xs = (tid < 80);
    const int  xrow  = tid >> 2;
    const int  xj    = tid & 3;
    const int  xgy   = y0 - 2 + xrow;
    const int  gx0   = x0 + 4 * xj;           // always 0..188: quad in-bounds
    const bool xrowin = (xgy >= 0) && (xgy < HH);
    const bool lok    = (gx0 > 0);            // left float2 (gx0-2,gx0-1) in-bounds
    const bool rok    = (gx0 + 4 < WW);       // right float2 (gx0+4,gx0+5) in-bounds

    const int  t2   = tid - 80;
    const bool is_raw = (tid >= 80) && (tid < 200);
    const int  rrow = t2 / 6;
    const int  rq   = t2 - rrow * 6;
    const int  rgy  = y0 - 2 + rrow;
    const int  rgx  = x0 - 4 + 4 * rq;
    const bool rrowin = (rgy >= 0) && (rgy < HH);
    const bool rxin   = (rgx >= 0) && (rgx <= WW - 4);

    float4 qm = make_float4(0,0,0,0), qf = qm, prm_ = qm, prf_ = qm;
    float2 lm = make_float2(0,0), lf = lm, rm2 = lm, rf2 = lm;

    auto prefetch = [&](int zz) {
        if (is_xs) {
            qm = qf = make_float4(0,0,0,0);
            lm = lf = rm2 = rf2 = make_float2(0,0);
            if (zz >= 0 && zz < DD && xrowin) {
                const float* pm = mimg + ((size_t)zz * HH + xgy) * WW;
                const float* pf = fimg + ((size_t)zz * HH + xgy) * WW;
                qm = *(const float4*)(pm + gx0);
                qf = *(const float4*)(pf + gx0);
                if (lok) { lm  = *(const float2*)(pm + gx0 - 2); lf  = *(const float2*)(pf + gx0 - 2); }
                if (rok) { rm2 = *(const float2*)(pm + gx0 + 4); rf2 = *(const float2*)(pf + gx0 + 4); }
            }
        } else if (is_raw) {
            prm_ = prf_ = make_float4(0,0,0,0);
            if (zz >= 0 && zz < DD && rrowin && rxin) {
                prm_ = *(const float4*)(mimg + ((size_t)zz * HH + rgy) * WW + rgx);
                prf_ = *(const float4*)(fimg + ((size_t)zz * HH + rgy) * WW + rgx);
            }
        }
    };

    auto commit = [&](int slot) {
        if (is_xs) {
            float a[8]  = {lm.x, lm.y, qm.x, qm.y, qm.z, qm.w, rm2.x, rm2.y};
            float bb[8] = {lf.x, lf.y, qf.x, qf.y, qf.z, qf.w, rf2.x, rf2.y};
            float s, w0, w1, w2, w3;
            // field 0: m
            s = a[0]+a[1]+a[2]+a[3]+a[4]; w0=s; s+=a[5]-a[0]; w1=s; s+=a[6]-a[1]; w2=s; s+=a[7]-a[2]; w3=s;
            *(float4*)&xs[0][xrow][4*xj] = make_float4(w0,w1,w2,w3);
            // field 1: f
            s = bb[0]+bb[1]+bb[2]+bb[3]+bb[4]; w0=s; s+=bb[5]-bb[0]; w1=s; s+=bb[6]-bb[1]; w2=s; s+=bb[7]-bb[2]; w3=s;
            *(float4*)&xs[1][xrow][4*xj] = make_float4(w0,w1,w2,w3);
            // field 2: mm
            {
                float p[8];
#pragma unroll
                for (int i = 0; i < 8; ++i) p[i] = a[i]*a[i];
                s = p[0]+p[1]+p[2]+p[3]+p[4]; w0=s; s+=p[5]-p[0]; w1=s; s+=p[6]-p[1]; w2=s; s+=p[7]-p[2]; w3=s;
                *(float4*)&xs[2][xrow][4*xj] = make_float4(w0,w1,w2,w3);
            }
            // field 3: ff
            {
                float p[8];
#pragma unroll
                for (int i = 0; i < 8; ++i) p[i] = bb[i]*bb[i];
                s = p[0]+p[1]+p[2]+p[3]+p[4]; w0=s; s+=p[5]-p[0]; w1=s; s+=p[6]-p[1]; w2=s; s+=p[7]-p[2]; w3=s;
                *(float4*)&xs[3][xrow][4*xj] = make_float4(w0,w1,w2,w3);
            }
            // field 4: mf
            {
                float p[8];
#pragma unroll
                for (int i = 0; i < 8; ++i) p[i] = a[i]*bb[i];
                s = p[0]+p[1]+p[2]+p[3]+p[4]; w0=s; s+=p[5]-p[0]; w1=s; s+=p[6]-p[1]; w2=s; s+=p[7]-p[2]; w3=s;
                *(float4*)&xs[4][xrow][4*xj] = make_float4(w0,w1,w2,w3);
            }
        } else if (is_raw) {
            *(float4*)&rawm[slot][rrow][4*rq] = prm_;
            *(float4*)&rawf[slot][rrow][4*rq] = prf_;
        }
    };

    auto ytask = [&](int t) {
        const int x = t & 15;
        const int c = (t >> 4) & 3;
        const int f = t >> 6;
        const float* col = &xs[f][4*c][x];    // stride 20 along y
        const float v0 = col[0],   v1 = col[20],  v2 = col[40],  v3 = col[60];
        const float v4 = col[80],  v5 = col[100], v6 = col[120], v7 = col[140];
        float s = v0 + v1 + v2 + v3 + v4;
        float* bp = &box[f][x][4*c];
        bp[0] = s; s += v5 - v0;
        bp[1] = s; s += v6 - v1;
        bp[2] = s; s += v7 - v2;
        bp[3] = s;
    };

    // per-thread 5-deep shift ring of 2D sums (5 fields) + z-center reg ring
    float ring[5][5];
#pragma unroll
    for (int s = 0; s < 5; ++s)
#pragma unroll
        for (int f = 0; f < 5; ++f) ring[s][f] = 0.f;
    float cm0=0, cm1=0, cm2=0, cm3=0, cf0=0, cf1=0, cf2=0, cf3=0;

    prefetch(z0 - 2);

    for (int n = 0; n < ZSEG + 4; ++n) {
        const int zc   = z0 - 2 + n;
        const int slot = n & 3;

        commit(slot);
        prefetch(zc + 1);                 // in flight across both barriers

        const int  z = zc - 2;
        const bool emitv = (n >= 4);
        int um = 0, uf = 0;
        if (emitv) {
            const int vidx = (z * HH + (y0 + ty)) * WW + (x0 + tx);
            um = __builtin_nontemporal_load(mmask + vidx);
            uf = __builtin_nontemporal_load(fmask + vidx);
        }

        __syncthreads();                  // A: raw[slot] + xs visible

        ytask(tid);
        if (tid < 64) ytask(tid + 256);

        __syncthreads();                  // C: box visible

        // fresh centers (slice zc) -> z register ring
        {
            const float ncm = rawm[slot][ty + 2][tx + 4];
            const float ncf = rawf[slot][ty + 2][tx + 4];
            cm3 = cm2; cm2 = cm1; cm1 = cm0; cm0 = ncm;
            cf3 = cf2; cf2 = cf1; cf1 = cf0; cf0 = ncf;
        }

        // this slice's 2D sums -> shift ring
        float s2d[5];
#pragma unroll
        for (int f = 0; f < 5; ++f) s2d[f] = box[f][tx][ty];
#pragma unroll
        for (int s = 0; s < 4; ++s)
#pragma unroll
            for (int f = 0; f < 5; ++f) ring[s][f] = ring[s + 1][f];
#pragma unroll
        for (int f = 0; f < 5; ++f) ring[4][f] = s2d[f];

        if (emitv) {
            float sum_m = 0.f, sum_f = 0.f, sum_mm = 0.f, sum_ff = 0.f, sum_mf = 0.f;
#pragma unroll
            for (int s = 0; s < 5; ++s) {
                sum_m  += ring[s][0];
                sum_f  += ring[s][1];
                sum_mm += ring[s][2];
                sum_ff += ring[s][3];
                sum_mf += ring[s][4];
            }
            const int gx = x0 + tx, gy = y0 + ty;
            const int slot2 = (n + 2) & 3;        // slice zc-2 (== z)
            const int cy = ty + 2, cx = tx + 4;
            const float mc = cm2;                 // center at z
            const float fc = cf2;

            float gxm, gxf, gym, gyf, gzm, gzf;
            if (gx == 0)          { gxm = rawm[slot2][cy][cx + 1] - mc;  gxf = rawf[slot2][cy][cx + 1] - fc; }
            else if (gx == WW-1)  { gxm = mc - rawm[slot2][cy][cx - 1];  gxf = fc - rawf[slot2][cy][cx - 1]; }
            else {
                gxm = 0.5f * (rawm[slot2][cy][cx + 1] - rawm[slot2][cy][cx - 1]);
                gxf = 0.5f * (rawf[slot2][cy][cx + 1] - rawf[slot2][cy][cx - 1]);
            }
            if (gy == 0)          { gym = rawm[slot2][cy + 1][cx] - mc;  gyf = rawf[slot2][cy + 1][cx] - fc; }
            else if (gy == HH-1)  { gym = mc - rawm[slot2][cy - 1][cx];  gyf = fc - rawf[slot2][cy - 1][cx]; }
            else {
                gym = 0.5f * (rawm[slot2][cy + 1][cx] - rawm[slot2][cy - 1][cx]);
                gyf = 0.5f * (rawf[slot2][cy + 1][cx] - rawf[slot2][cy - 1][cx]);
            }
            if (z == 0)           { gzm = cm1 - mc;            gzf = cf1 - fc; }
            else if (z == DD-1)   { gzm = mc - cm3;            gzf = fc - cf3; }
            else                  { gzm = 0.5f * (cm1 - cm3);  gzf = 0.5f * (cf1 - cf3); }

            const float u = ((um != 0) || (uf != 0)) ? 1.0f : 0.0f;

            const float npix = 125.0f;
            const float inv_npix = 1.0f / 125.0f;
            const float mean_m = sum_m * inv_npix;
            const float mean_f = sum_f * inv_npix;
            const float var_m = sum_mm - 2.0f * mean_m * sum_m + npix * mean_m * mean_m;
            const float var_f = sum_ff - 2.0f * mean_f * sum_f + npix * mean_f * mean_f;
            const float var_mf = var_m * var_f;
            const float cross = sum_mf - mean_f * sum_m - mean_m * sum_f + npix * mean_m * mean_f;
            const float mmc = mc - mean_m;
            const float fmc = fc - mean_f;
            const bool ok = (var_mf > 1e-5f) && (var_f > 1e-5f) && (fmc != 0.0f) && (mmc != 0.0f);
            float factor = 0.0f;
            if (ok) factor = 2.0f * cross / var_mf * (mmc - cross * fmc / var_f);

            const int vidx = (z * HH + gy) * WW + gx;
            const float nf = -factor * 0.5f * u;
            out[vidx]            = nf * (gzm + gzf);   // ch 0: d/dD
            out[NVOX + vidx]     = nf * (gym + gyf);   // ch 1: d/dH
            out[2 * NVOX + vidx] = nf * (gxm + gxf);   // ch 2: d/dW
        }
        // no trailing barrier: next raw write slot (n+1)&3 is disjoint from
        // read slots {n, n+2}&3; xs/box next writes are fenced by next A / C.
    }
}

extern "C" void kernel_launch(void* const* d_in, const int* in_sizes, int n_in,
                              void* d_out, int out_size, void* d_ws, size_t ws_size,
                              hipStream_t stream)
{
    const float* mimg  = (const float*)d_in[0];
    const float* fimg  = (const float*)d_in[1];
    const int*   mmask = (const int*)d_in[2];
    const int*   fmask = (const int*)d_in[3];
    float* out = (float*)d_out;

    dim3 grid(NBX * NBY * NBZ, 1, 1);   // 1728 blocks
    dim3 block(256, 1, 1);
    hipLaunchKernelGGL(ncc_forces_kernel, grid, block, 0, stream,
                       mimg, fimg, mmask, fmask, out);
}

// Round 5
// 213.846 us; speedup vs baseline: 1.1577x; 1.1577x over previous
//
#include <hip/hip_runtime.h>

// NCC forces, 192^3 fp32. Round 5: R3 skeleton + LDS bandwidth-efficiency.
// Model: R3 was LDS-pipe-bound (~1360 DS-cyc per block-iter of ~1667 budget).
// R4 failed by concentrating work on 2 waves; here phases stay spread.
//  - x-phase: 80 chunk-of-4 tasks, vector reads (2xb128+b64 per image),
//    sliding-window 5 fields in regs, 5 b128 writes. ~165 cyc (was ~435).
//  - y-phase: 160 chunk-of-8 sliding tasks, 12 strided b32 rd + 2 b128 wr
//    into ping-pong box buffer. ~290+60 cyc (was ~580).
//  - emit consumes box from PREVIOUS iter (ping-pong) -> still 2 barriers.
//  - z-grad centers in 5-deep register ring; raw ring 5-deep (slot-disjoint,
//    no trailing barrier). LDS 40000 B -> 4 blocks/CU.
//  - ZSEG 12 -> 2304 blocks; XCD swizzle kept; NT mask loads; plain stores.

#define DD 192
#define HH 192
#define WW 192
#define NVOX (DD * HH * WW)
#define TS 16
#define RR 20            // staged rows (y: y0-2 .. y0+17)
#define RW 24            // staged row width (x: x0-4 .. x0+19)
#define ZSEG 12
#define NBX 12
#define NBY 12
#define NBZ 16
#define PER_XCD ((NBX * NBY * NBZ) / 8)   // 288

__global__ __launch_bounds__(256)
void ncc_forces_kernel(const float* __restrict__ mimg,
                       const float* __restrict__ fimg,
                       const int*   __restrict__ mmask,
                       const int*   __restrict__ fmask,
                       float* __restrict__ out)
{
    __shared__ float rawm[5][RR][RW];     // 9600 B
    __shared__ float rawf[5][RR][RW];     // 9600 B
    __shared__ float xs[5][RR][20];       // 8000 B  [field][yrow][xo], pitch 20 (bank-checked)
    __shared__ float box[2][5][TS][20];   // 12800 B [pp][field][x][yout], pitch 20

    // XCD swizzle: XCD k gets 288 consecutive logical blocks (2 z-slabs)
    const int b  = blockIdx.x;
    const int L  = (b & 7) * PER_XCD + (b >> 3);
    const int bz = L / (NBX * NBY);
    const int r_ = L - bz * (NBX * NBY);
    const int by = r_ / NBX;
    const int bx = r_ - by * NBX;

    const int tid = threadIdx.x;
    const int tx = tid & 15, ty = tid >> 4;
    const int x0 = bx * TS, y0 = by * TS, z0 = bz * ZSEG;

    // ---- staging roles: 240 lanes = 2 images x 20 rows x 6 quads ----
    const int  simg   = tid / 120;            // 0,1 stager; 2 idle
    const bool stager = (simg < 2);
    const int  st     = tid - simg * 120;
    const int  srow   = st / 6;
    const int  squad  = st - srow * 6;
    const int  sgy    = y0 - 2 + srow;
    const int  sgx    = x0 - 4 + 4 * squad;   // quads all-in or all-out (x0%16==0)
    const bool sin_   = (sgy >= 0) && (sgy < HH) && (sgx >= 0) && (sgx <= WW - 4);
    const float* sptr = (simg == 1) ? fimg : mimg;
    float* sldsb = (simg == 1) ? &rawf[0][0][0] : &rawm[0][0][0];
    const int  sloff  = srow * RW + 4 * squad;

    float4 pref = make_float4(0, 0, 0, 0);
    auto prefetch = [&](int zz) {
        pref = make_float4(0, 0, 0, 0);
        if (stager && sin_ && zz >= 0 && zz < DD)
            pref = *(const float4*)(sptr + ((size_t)zz * HH + sgy) * WW + sgx);
    };

    // per-thread rings
    float ring[5][5];
#pragma unroll
    for (int s = 0; s < 5; ++s)
#pragma unroll
        for (int f = 0; f < 5; ++f) ring[s][f] = 0.f;
    float cm[5] = {0, 0, 0, 0, 0}, cf[5] = {0, 0, 0, 0, 0};

    prefetch(z0 - 2);

    for (int n = 0; n <= ZSEG + 4; ++n) {
        const int zc = z0 - 2 + n;           // slice committed this iter
        const int sw = n % 5;                // raw write slot
        const int z  = zc - 3;               // slice emitted this iter
        const bool emitv = (n >= 5);

        // ---- commit staged slice zc; issue loads for zc+1 ----
        if (stager) *(float4*)(sldsb + sw * (RR * RW) + sloff) = pref;
        prefetch(zc + 1);

        int um = 0, uf = 0;
        int vidx = 0;
        if (emitv) {
            vidx = (z * HH + (y0 + ty)) * WW + (x0 + tx);
            um = __builtin_nontemporal_load(mmask + vidx);
            uf = __builtin_nontemporal_load(fmask + vidx);
        }

        __syncthreads();   // A: raw[sw] ready; box[(n-1)&1] (y of n-1) ready

        // ---- x-phase: 80 chunk-of-4 tasks, vector LDS IO ----
        if (tid < 80) {
            const int yy = tid >> 2;          // 0..19
            const int t4 = (tid & 3) * 4;     // 0,4,8,12
            const float4 A0 = *(const float4*)&rawm[sw][yy][t4];
            const float4 A1 = *(const float4*)&rawm[sw][yy][t4 + 4];
            const float2 A2 = *(const float2*)&rawm[sw][yy][t4 + 8];
            const float4 B0 = *(const float4*)&rawf[sw][yy][t4];
            const float4 B1 = *(const float4*)&rawf[sw][yy][t4 + 4];
            const float2 B2 = *(const float2*)&rawf[sw][yy][t4 + 8];
            const float a[10] = {A0.x, A0.y, A0.z, A0.w, A1.x, A1.y, A1.z, A1.w, A2.x, A2.y};
            const float bb[10] = {B0.x, B0.y, B0.z, B0.w, B1.x, B1.y, B1.z, B1.w, B2.x, B2.y};
            // window for output xo=t4+j: indices j+2..j+6
            float p[10], s, w0, w1, w2, w3;
#pragma unroll
            for (int f = 0; f < 5; ++f) {
#pragma unroll
                for (int i = 2; i < 10; ++i) {
                    p[i] = (f == 0) ? a[i] : (f == 1) ? bb[i] :
                           (f == 2) ? a[i] * a[i] : (f == 3) ? bb[i] * bb[i] : a[i] * bb[i];
                }
                s = p[2] + p[3] + p[4] + p[5] + p[6]; w0 = s;
                s += p[7] - p[2]; w1 = s;
                s += p[8] - p[3]; w2 = s;
                s += p[9] - p[4]; w3 = s;
                *(float4*)&xs[f][yy][t4] = make_float4(w0, w1, w2, w3);
            }
        }

        // ---- emit slice z (uses box from iter n-1 = 2D sums of slice zc-1) ----
        // centers: fresh slice zc -> register ring
        {
            const float ncm = rawm[sw][ty + 2][tx + 4];
            const float ncf = rawf[sw][ty + 2][tx + 4];
#pragma unroll
            for (int s2 = 4; s2 > 0; --s2) { cm[s2] = cm[s2 - 1]; cf[s2] = cf[s2 - 1]; }
            cm[0] = ncm; cf[0] = ncf;
        }
        if (n >= 1) {
            const int pp = (n - 1) & 1;
            float s2d[5];
#pragma unroll
            for (int f = 0; f < 5; ++f) s2d[f] = box[pp][f][tx][ty];
#pragma unroll
            for (int s = 0; s < 4; ++s)
#pragma unroll
                for (int f = 0; f < 5; ++f) ring[s][f] = ring[s + 1][f];
#pragma unroll
            for (int f = 0; f < 5; ++f) ring[4][f] = s2d[f];
        }

        if (emitv) {
            float sum_m = 0.f, sum_f = 0.f, sum_mm = 0.f, sum_ff = 0.f, sum_mf = 0.f;
#pragma unroll
            for (int s = 0; s < 5; ++s) {
                sum_m  += ring[s][0];
                sum_f  += ring[s][1];
                sum_mm += ring[s][2];
                sum_ff += ring[s][3];
                sum_mf += ring[s][4];
            }
            const int gx = x0 + tx, gy = y0 + ty;
            const int s2 = (n + 2) % 5;       // slot of slice z (= zc-3)
            const int cy = ty + 2, cx = tx + 4;
            const float mc = cm[3];           // center at z
            const float fc = cf[3];

            float gxm, gxf, gym, gyf, gzm, gzf;
            if (gx == 0)          { gxm = rawm[s2][cy][cx + 1] - mc;  gxf = rawf[s2][cy][cx + 1] - fc; }
            else if (gx == WW-1)  { gxm = mc - rawm[s2][cy][cx - 1];  gxf = fc - rawf[s2][cy][cx - 1]; }
            else {
                gxm = 0.5f * (rawm[s2][cy][cx + 1] - rawm[s2][cy][cx - 1]);
                gxf = 0.5f * (rawf[s2][cy][cx + 1] - rawf[s2][cy][cx - 1]);
            }
            if (gy == 0)          { gym = rawm[s2][cy + 1][cx] - mc;  gyf = rawf[s2][cy + 1][cx] - fc; }
            else if (gy == HH-1)  { gym = mc - rawm[s2][cy - 1][cx];  gyf = fc - rawf[s2][cy - 1][cx]; }
            else {
                gym = 0.5f * (rawm[s2][cy + 1][cx] - rawm[s2][cy - 1][cx]);
                gyf = 0.5f * (rawf[s2][cy + 1][cx] - rawf[s2][cy - 1][cx]);
            }
            if (z == 0)           { gzm = cm[2] - mc;             gzf = cf[2] - fc; }
            else if (z == DD-1)   { gzm = mc - cm[4];             gzf = fc - cf[4]; }
            else                  { gzm = 0.5f * (cm[2] - cm[4]); gzf = 0.5f * (cf[2] - cf[4]); }

            const float u = ((um != 0) || (uf != 0)) ? 1.0f : 0.0f;

            const float npix = 125.0f;
            const float inv_npix = 1.0f / 125.0f;
            const float mean_m = sum_m * inv_npix;
            const float mean_f = sum_f * inv_npix;
            const float var_m = sum_mm - 2.0f * mean_m * sum_m + npix * mean_m * mean_m;
            const float var_f = sum_ff - 2.0f * mean_f * sum_f + npix * mean_f * mean_f;
            const float var_mf = var_m * var_f;
            const float cross = sum_mf - mean_f * sum_m - mean_m * sum_f + npix * mean_m * mean_f;
            const float mmc = mc - mean_m;
            const float fmc = fc - mean_f;
            const bool ok = (var_mf > 1e-5f) && (var_f > 1e-5f) && (fmc != 0.0f) && (mmc != 0.0f);
            float factor = 0.0f;
            if (ok) factor = 2.0f * cross / var_mf * (mmc - cross * fmc / var_f);

            const float nf = -factor * 0.5f * u;
            out[vidx]            = nf * (gzm + gzf);   // ch 0: d/dD
            out[NVOX + vidx]     = nf * (gym + gyf);   // ch 1: d/dH
            out[2 * NVOX + vidx] = nf * (gxm + gxf);   // ch 2: d/dW
        }

        __syncthreads();   // B: xs ready (and emit reads of box/raw done)

        // ---- y-phase: 160 chunk-of-8 sliding tasks -> box[n&1] ----
        if (tid < 160) {
            const int x  = tid & 15;
            const int c8 = ((tid >> 4) & 1) * 8;   // 0 or 8
            const int f  = tid >> 5;               // 0..4
            float v[12];
#pragma unroll
            for (int j = 0; j < 12; ++j) v[j] = xs[f][c8 + j][x];
            float o[8];
            float s = v[0] + v[1] + v[2] + v[3] + v[4];
            o[0] = s;
#pragma unroll
            for (int j = 1; j < 8; ++j) { s += v[j + 4] - v[j - 1]; o[j] = s; }
            float* bp = &box[n & 1][f][x][c8];
            *(float4*)bp       = make_float4(o[0], o[1], o[2], o[3]);
            *(float4*)(bp + 4) = make_float4(o[4], o[5], o[6], o[7]);
        }
        // no trailing barrier:
        //  - next commit writes raw[(n+1)%5]; readers this iter used {n, n+2}%5.
        //  - next x-phase (writes xs) is fenced by next barrier A.
        //  - box[n&1] is read at emit(n+1) after A(n+1), rewritten at y(n+2).
    }
}

extern "C" void kernel_launch(void* const* d_in, const int* in_sizes, int n_in,
                              void* d_out, int out_size, void* d_ws, size_t ws_size,
                              hipStream_t stream)
{
    const float* mimg  = (const float*)d_in[0];
    const float* fimg  = (const float*)d_in[1];
    const int*   mmask = (const int*)d_in[2];
    const int*   fmask = (const int*)d_in[3];
    float* out = (float*)d_out;

    dim3 grid(NBX * NBY * NBZ, 1, 1);   // 2304 blocks
    dim3 block(256, 1, 1);
    hipLaunchKernelGGL(ncc_forces_kernel, grid, block, 0, stream,
                       mimg, fimg, mmask, fmask, out);
}